// Round 2
// baseline (260.637 us; speedup 1.0000x reference)
//
#include <hip/hip_runtime.h>

#define NB    65536
#define NT    512
#define SLEN  12
#define BLOCK 256
#define ROWS  8      // rows per iteration (2 per wave)
#define ITERS 4      // row-groups per block -> grid 2048 = exactly 8 blocks/CU
#define CHUNKS 32    // chunks per row = lanes per 32-lane row group
#define CLEN  16     // timesteps per chunk

// Affine-scan decomposition, chain-free form.
// x_t = A x_{t-1} + b_t, b_t = d_t * v with d_t = alpha*(y_t - s_t), v=(1,beta).
// Zero-init chunk outputs are a causal convolution with scalar kernel
// cu_i = [1,1]A^i v ; zero-init end state = sum d_j * w_{15-j}, w_i = A^i v.
// All per-step FMAs are independent (no 16-step dependent chain).
// Cross-chunk combine: Kogge-Stone affine scan (constant matrices M^(2^d)).
// Chunk 0 init folds in exactly: d_0 := 0, end state += A^15*(y0,trend0),
// correction uses u_k (not u_{k+1}) with S = (y0, trend0).
__global__ __launch_bounds__(BLOCK) void holtwinters_kernel(
    const float* __restrict__ series,
    const int*   __restrict__ shifts,
    const float* __restrict__ alpha_p,
    const float* __restrict__ beta_p,
    const float* __restrict__ init_season,
    const float* __restrict__ trend0_p,
    float*       __restrict__ out)
{
    __shared__ float  ss[SLEN];
    __shared__ float2 u[CLEN + 1];   // u_j = [1,1]A^j, j=0..16
    __shared__ float  cu[CLEN];      // cu_i = [1,1]A^i v   (scalar conv kernel)
    __shared__ float2 w[CLEN];       // w_i  = A^i v        (end-state kernel)
    __shared__ float4 Mp[5];         // M^(2^d), M = A^16   (scan matrices)
    __shared__ float4 P15;           // A^15 (m00,m01,m10,m11)

    const int t = threadIdx.x;
    const float alpha  = alpha_p[0];
    const float beta   = beta_p[0];
    const float oma    = 1.0f - alpha;
    const float omb    = 1.0f - beta;
    const float trend0 = trend0_p[0];

    if (t < SLEN) ss[t] = init_season[t];
    if (t == 0) {
        const float a00 = oma, a01 = oma;
        const float a10 = -alpha * beta, a11 = beta * oma + omb;
        float p00 = 1.f, p01 = 0.f, p10 = 0.f, p11 = 1.f;   // A^0
        u[0]  = make_float2(1.f, 1.f);
        cu[0] = 1.0f + beta;                                // [1,1]v
        w[0]  = make_float2(1.0f, beta);                    // v
        for (int j = 1; j <= CLEN; ++j) {                   // P_j = A^j
            const float n00 = p00*a00 + p01*a10;
            const float n01 = p00*a01 + p01*a11;
            const float n10 = p10*a00 + p11*a10;
            const float n11 = p10*a01 + p11*a11;
            p00 = n00; p01 = n01; p10 = n10; p11 = n11;
            u[j] = make_float2(p00 + p10, p01 + p11);       // column sums
            if (j < CLEN) {
                cu[j] = (p00 + p10) + beta * (p01 + p11);   // u_j . v
                w[j]  = make_float2(p00 + p01*beta, p10 + p11*beta); // P_j v
            }
            if (j == CLEN - 1) P15 = make_float4(p00, p01, p10, p11);
        }
        float m00 = p00, m01 = p01, m10 = p10, m11 = p11;   // A^16
        for (int dlev = 0; dlev < 5; ++dlev) {              // A^16..A^256
            Mp[dlev] = make_float4(m00, m01, m10, m11);
            const float n00 = m00*m00 + m01*m10;
            const float n01 = m00*m01 + m01*m11;
            const float n10 = m10*m00 + m11*m10;
            const float n11 = m10*m01 + m11*m11;
            m00 = n00; m01 = n01; m10 = n10; m11 = n11;
        }
    }
    __syncthreads();   // the only barrier

    const int r = t >> 5;        // row within group
    const int c = t & 31;        // chunk within row

    for (int it = 0; it < ITERS; ++it) {
        const int row   = (blockIdx.x * ITERS + it) * ROWS + r;
        const int shift = shifts[row];
        const int sidx0 = ((c * CLEN - shift) % SLEN + SLEN) % SLEN;

        // loads: 4x float4 at 64B stride; each 128B line fully consumed by
        // 2 lanes x 4 back-to-back instructions.
        const float* __restrict__ yb = series + (size_t)row * NT + c * CLEN;
        float yv[CLEN];
        *(float4*)&yv[0]  = *(const float4*)(yb + 0);
        *(float4*)&yv[4]  = *(const float4*)(yb + 4);
        *(float4*)&yv[8]  = *(const float4*)(yb + 8);
        *(float4*)&yv[12] = *(const float4*)(yb + 12);
        const float y0v = yv[0];

        // d_k = alpha*(y_k - s_k); y dies here (only d stays live)
        float d[CLEN];
        int sidx = sidx0;
        #pragma unroll
        for (int k = 0; k < CLEN; ++k) {
            const float s = ss[sidx];
            sidx = (sidx + 1 == SLEN) ? 0 : sidx + 1;
            d[k] = alpha * (yv[k] - s);
        }
        if (c == 0) d[0] = 0.0f;       // chunk 0: step 0 is init, not recurrence

        // zero-init end state: E = sum_j d_j * w[15-j]  (independent FMAs)
        float Ex = 0.f, Ey = 0.f;
        #pragma unroll
        for (int j = 0; j < CLEN; ++j) {
            const float2 wj = w[CLEN - 1 - j];
            Ex = fmaf(d[j], wj.x, Ex);
            Ey = fmaf(d[j], wj.y, Ey);
        }
        {   // chunk 0 exact end state: += A^15 * (y0, trend0)
            const float4 p = P15;
            const float ax = fmaf(p.x, y0v, p.y * trend0);
            const float ay = fmaf(p.z, y0v, p.w * trend0);
            if (c == 0) { Ex += ax; Ey += ay; }
        }

        // Kogge-Stone inclusive affine scan over the 32 chunks of the row
        #pragma unroll
        for (int dlev = 0; dlev < 5; ++dlev) {
            const float4 m  = Mp[dlev];
            const int    dd = 1 << dlev;
            const float gx = __shfl_up(Ex, dd, CHUNKS);
            const float gy = __shfl_up(Ey, dd, CHUNKS);
            if (c >= dd) {
                Ex = fmaf(m.x, gx, fmaf(m.y, gy, Ex));
                Ey = fmaf(m.z, gx, fmaf(m.w, gy, Ey));
            }
        }
        // entering state of chunk c = end state of chunk c-1
        float Sx = __shfl_up(Ex, 1, CHUNKS);
        float Sy = __shfl_up(Ey, 1, CHUNKS);
        if (c == 0) { Sx = y0v; Sy = trend0; }
        const int off = (c == 0) ? 0 : 1;   // correction exponent u[k+off]

        // outputs: o_k = s_k + u[k+off].S + sum_{j<=k} cu[k-j]*d_j
        float o[CLEN];
        sidx = sidx0;
        #pragma unroll
        for (int k = 0; k < CLEN; ++k) {
            const float s = ss[sidx];
            sidx = (sidx + 1 == SLEN) ? 0 : sidx + 1;
            const float2 uk = u[k + off];
            float acc = fmaf(uk.x, Sx, fmaf(uk.y, Sy, s));
            #pragma unroll
            for (int j = 0; j <= k; ++j)
                acc = fmaf(cu[k - j], d[j], acc);
            o[k] = acc;
        }
        if (c == 0) o[0] = y0v + trend0;    // res0 = y0 + init_trend

        float* __restrict__ ob = out + (size_t)row * NT + c * CLEN;
        *(float4*)(ob + 0)  = *(float4*)&o[0];
        *(float4*)(ob + 4)  = *(float4*)&o[4];
        *(float4*)(ob + 8)  = *(float4*)&o[8];
        *(float4*)(ob + 12) = *(float4*)&o[12];
    }
}

extern "C" void kernel_launch(void* const* d_in, const int* in_sizes, int n_in,
                              void* d_out, int out_size, void* d_ws, size_t ws_size,
                              hipStream_t stream) {
    // inputs: 0=series(B*T f32), 1=series_shifts(B i32), 2=alpha, 3=beta,
    //         4=gamma(unused), 5=init_season(12 f32), 6=init_trend, 7=n_preds(unused)
    const float* series      = (const float*)d_in[0];
    const int*   shifts      = (const int*)  d_in[1];
    const float* alpha       = (const float*)d_in[2];
    const float* beta        = (const float*)d_in[3];
    const float* init_season = (const float*)d_in[5];
    const float* init_trend  = (const float*)d_in[6];
    float*       out         = (float*)d_out;

    dim3 block(BLOCK);
    dim3 grid(NB / (ROWS * ITERS));   // 2048 blocks = exactly 8 per CU
    hipLaunchKernelGGL(holtwinters_kernel, grid, block, 0, stream,
                       series, shifts, alpha, beta, init_season, init_trend, out);
}